// Round 4
// baseline (140.498 us; speedup 1.0000x reference)
//
#include <hip/hip_runtime.h>
#include <hip/hip_bf16.h>

#define B_N 16384
#define TAU 0.25f
#define GS 68     // G leading dim (floats); 16B-aligned rows
#define YS 132    // Y leading dim (floats); EVEN -> 16B-aligned rows for f32x4 reads
#define DS 68     // D_lds leading dim (floats); 16B-aligned rows

typedef float f32x4 __attribute__((ext_vector_type(4)));
typedef short s16x8 __attribute__((ext_vector_type(8)));

__device__ __forceinline__ void gl_lds16(const void* g, void* l) {
    __builtin_amdgcn_global_load_lds(
        (const __attribute__((address_space(1))) void*)g,
        (__attribute__((address_space(3))) void*)l, 16, 0, 0);
}

__device__ __forceinline__ unsigned short bf16_bits(float v) {
    __hip_bfloat16 h = __float2bfloat16(v);
    return *reinterpret_cast<unsigned short*>(&h);
}

__device__ __forceinline__ float readlane_f(float v, int l) {
    return __int_as_float(__builtin_amdgcn_readlane(__float_as_int(v), l));
}

// ---------------------------------------------------------------------------
// Kernel 1 (merged): blocks 0..63 = per-cluster prep (512 thr = 8 waves);
// blocks 64..191 = convert. (byte-identical to R11/R12)
// ---------------------------------------------------------------------------
__global__ __launch_bounds__(512) void prep_convert(const float* __restrict__ x,
                                                    const float* __restrict__ D,
                                                    unsigned short* __restrict__ xh,
                                                    float* __restrict__ nrm,
                                                    float* __restrict__ Qg,
                                                    unsigned short* __restrict__ Bht,
                                                    float* __restrict__ out) {
    const int t = threadIdx.x;

    if (blockIdx.x >= 64) {
        // ---------------- convert path ----------------
        const int gid = (blockIdx.x - 64) * 512 + t;   // 0..65535 quarter-rows
        if (gid == 0) out[0] = 0.0f;
        const size_t base = (size_t)gid * 32;
        float s = 0.0f;
        #pragma unroll
        for (int c = 0; c < 8; ++c) {
            const f32x4 v = ((const f32x4*)(x + base))[c];
            s += v.x * v.x + v.y * v.y + v.z * v.z + v.w * v.w;
            ushort4 h;
            h.x = bf16_bits(v.x); h.y = bf16_bits(v.y);
            h.z = bf16_bits(v.z); h.w = bf16_bits(v.w);
            ((ushort4*)(xh + base))[c] = h;
        }
        s += __shfl_xor(s, 1, 64);
        s += __shfl_xor(s, 2, 64);
        if ((gid & 3) == 0) nrm[gid >> 2] = s;
        return;
    }

    // ---------------- prep path ----------------
    __shared__ float Y[64 * YS];                      // D^T (fp32), read by Phase Z
    __shared__ __align__(16) float Dl[128 * DS];      // D row-major, read by Phase B
    __shared__ __align__(16) float G[64 * GS + 64];   // gram -> L (lower) + Linv (upper); tail = 1/L[i][i]
    __shared__ __align__(16) float Lti[8 * 8 * 8];    // 8x8 diag-block inverses
    const int n = blockIdx.x;
    const float* Dn = D + (size_t)n * 8192;

    // Phase A: Y[j][c] = Dn[c][j] (transposed) + Dl[c][j] (row-major)
    for (int e4 = t; e4 < 2048; e4 += 512) {
        const int c = e4 >> 4, j4 = (e4 & 15) * 4;
        const f32x4 v = ((const f32x4*)Dn)[e4];
        *(f32x4*)&Dl[c * DS + j4] = v;
        Y[(j4 + 0) * YS + c] = v.x;
        Y[(j4 + 1) * YS + c] = v.y;
        Y[(j4 + 2) * YS + c] = v.z;
        Y[(j4 + 3) * YS + c] = v.w;
    }
    __syncthreads();   // Dl ready for Phase B

    // Phase B: gram from LDS (broadcast-friendly), split over two c-halves
    {
        const int h = t >> 8;                          // 0 or 1
        const int a0 = (t & 15) * 4, b0 = ((t >> 4) & 15) * 4;
        const int i0 = h * 64;
        float acc[4][4] = {};
        #pragma unroll 4
        for (int i = i0; i < i0 + 64; ++i) {
            const f32x4 av = *(const f32x4*)&Dl[i * DS + a0];
            const f32x4 bv = *(const f32x4*)&Dl[i * DS + b0];
            const float aa[4] = {av.x, av.y, av.z, av.w};
            const float bb[4] = {bv.x, bv.y, bv.z, bv.w};
            #pragma unroll
            for (int p = 0; p < 4; ++p)
                #pragma unroll
                for (int q = 0; q < 4; ++q) acc[p][q] = fmaf(aa[p], bb[q], acc[p][q]);
        }
        if (h == 0) {
            #pragma unroll
            for (int p = 0; p < 4; ++p)
                #pragma unroll
                for (int q = 0; q < 4; ++q) G[(a0 + p) * GS + b0 + q] = acc[p][q];
        }
        __syncthreads();
        if (h == 1) {
            #pragma unroll
            for (int p = 0; p < 4; ++p)
                #pragma unroll
                for (int q = 0; q < 4; ++q) G[(a0 + p) * GS + b0 + q] += acc[p][q];
        }
    }
    __syncthreads();

    // Phase C: blocked Cholesky, register-resident 8x8 panels.
    #pragma unroll
    for (int p8 = 0; p8 < 8; ++p8) {
        const int pb = p8 * 8;
        if (t < 64) {
            const int lane = t;
            const f32x4 v0 = *(const f32x4*)&G[lane * GS + pb];
            const f32x4 v1 = *(const f32x4*)&G[lane * GS + pb + 4];
            float g[8] = {v0.x, v0.y, v0.z, v0.w, v1.x, v1.y, v1.z, v1.w};
            #pragma unroll
            for (int kk = 0; kk < 8; ++kk) {
                const int k = pb + kk;
                const float dk = readlane_f(g[kk], k);
                const float rinv = 1.0f / sqrtf(dk);
                const float lik = g[kk] * rinv;
                g[kk] = lik;
                if (lane == 0) G[64 * GS + k] = rinv;
                #pragma unroll
                for (int jj = kk + 1; jj < 8; ++jj) {
                    const float ljk = readlane_f(lik, pb + jj);
                    g[jj] -= lik * ljk;
                }
            }
            *(f32x4*)&G[lane * GS + pb]     = (f32x4){g[0], g[1], g[2], g[3]};
            *(f32x4*)&G[lane * GS + pb + 4] = (f32x4){g[4], g[5], g[6], g[7]};
        }
        __syncthreads();
        const int base = pb + 8;
        if (base < 64) {
            for (int i = base + (t >> 5); i < 64; i += 16) {
                const f32x4 Li0 = *(const f32x4*)&G[i * GS + pb];
                const f32x4 Li1 = *(const f32x4*)&G[i * GS + pb + 4];
                for (int j = base + (t & 31); j < 64; j += 32) {
                    const f32x4 Lj0 = *(const f32x4*)&G[j * GS + pb];
                    const f32x4 Lj1 = *(const f32x4*)&G[j * GS + pb + 4];
                    float s = G[i * GS + j];
                    s -= Li0.x * Lj0.x + Li0.y * Lj0.y + Li0.z * Lj0.z + Li0.w * Lj0.w;
                    s -= Li1.x * Lj1.x + Li1.y * Lj1.y + Li1.z * Lj1.z + Li1.w * Lj1.w;
                    G[i * GS + j] = s;
                }
            }
        }
        __syncthreads();
    }

    // Phase D: invert 8x8 diagonal blocks
    if (t < 64) {
        const int bi = t >> 3, c = t & 7;
        const int base = bi * 8;
        float m[8];
        #pragma unroll
        for (int r = 0; r < 8; ++r) {
            float s = (r == c) ? 1.0f : 0.0f;
            #pragma unroll
            for (int k = 0; k < r; ++k)
                s -= G[(base + r) * GS + base + k] * m[k];
            m[r] = s * G[64 * GS + base + r];
        }
        #pragma unroll
        for (int r = 0; r < 8; ++r) Lti[(base + r) * 8 + c] = m[r];
    }
    __syncthreads();

    // Phase L: assemble full Linv into G's strictly-upper triangle (transposed)
    {
        const int j = t >> 3, r = t & 7, jb = j >> 3;
        const float rinvj = G[64 * GS + j];
        for (int m8 = 0; m8 < 8; ++m8) {
            if (m8 >= jb) {
                const int g = m8 * 8 + r;
                float wv = (g == j) ? 1.0f : 0.0f;
                if (m8 > jb) {
                    #pragma unroll
                    for (int kk = 0; kk < 8; ++kk) {
                        const int gp = jb * 8 + kk;
                        const float liv = (gp > j) ? G[j * GS + gp]
                                         : ((gp == j) ? rinvj : 0.0f);
                        wv -= G[g * GS + gp] * liv;
                    }
                    for (int mm = jb + 1; mm < m8; ++mm) {
                        const f32x4 Lg0 = *(const f32x4*)&G[g * GS + mm * 8];
                        const f32x4 Lg1 = *(const f32x4*)&G[g * GS + mm * 8 + 4];
                        const f32x4 Mv0 = *(const f32x4*)&G[j * GS + mm * 8];
                        const f32x4 Mv1 = *(const f32x4*)&G[j * GS + mm * 8 + 4];
                        wv = fmaf(-Lg0.x, Mv0.x, wv);
                        wv = fmaf(-Lg0.y, Mv0.y, wv);
                        wv = fmaf(-Lg0.z, Mv0.z, wv);
                        wv = fmaf(-Lg0.w, Mv0.w, wv);
                        wv = fmaf(-Lg1.x, Mv1.x, wv);
                        wv = fmaf(-Lg1.y, Mv1.y, wv);
                        wv = fmaf(-Lg1.z, Mv1.z, wv);
                        wv = fmaf(-Lg1.w, Mv1.w, wv);
                    }
                }
                float z = 0.0f;
                #pragma unroll
                for (int rp = 0; rp < 8; ++rp) {
                    const float wrp = __shfl(wv, (t & 56) | rp, 64);
                    z = fmaf(Lti[g * 8 + rp], wrp, z);
                }
                if (g > j) G[j * GS + g] = z;
            }
            __syncthreads();
        }
    }

    // Phase Z: Z = Linv * Y (64x128, fp32), 4x4 per thread, epilogue fused.
    {
        const int jj = t >> 5;
        const int jz = (jj & 1) ? (15 - (jj >> 1)) : (jj >> 1);
        const int j0 = jz * 4, c0 = (t & 31) * 4;
        const f32x4 rv4 = *(const f32x4*)&G[64 * GS + j0];
        float acc[4][4] = {};   // [ej][ec]
        #pragma unroll 4
        for (int k = 0; k < j0; ++k) {
            const f32x4 lv = *(const f32x4*)&G[k * GS + j0];
            const f32x4 yv = *(const f32x4*)&Y[k * YS + c0];
            #pragma unroll
            for (int ej = 0; ej < 4; ++ej)
                #pragma unroll
                for (int ec = 0; ec < 4; ++ec)
                    acc[ej][ec] = fmaf(lv[ej], yv[ec], acc[ej][ec]);
        }
        #pragma unroll
        for (int kt = 0; kt < 4; ++kt) {
            const int k = j0 + kt;
            const f32x4 lq = *(const f32x4*)&G[k * GS + j0];
            const f32x4 yv = *(const f32x4*)&Y[k * YS + c0];
            #pragma unroll
            for (int ej = 0; ej < 4; ++ej) {
                const int jjj = j0 + ej;
                const float lsel = (jjj > k) ? lq[ej] : ((jjj == k) ? rv4[ej] : 0.0f);
                #pragma unroll
                for (int ec = 0; ec < 4; ++ec)
                    acc[ej][ec] = fmaf(lsel, yv[ec], acc[ej][ec]);
            }
        }
        #pragma unroll
        for (int ec = 0; ec < 4; ++ec) {
            *(f32x4*)&Qg[(size_t)n * 8192 + (c0 + ec) * 64 + j0] =
                (f32x4){acc[0][ec], acc[1][ec], acc[2][ec], acc[3][ec]};
        }
        #pragma unroll
        for (int ej = 0; ej < 4; ++ej) {
            ushort4 h;
            h.x = bf16_bits(acc[ej][0]); h.y = bf16_bits(acc[ej][1]);
            h.z = bf16_bits(acc[ej][2]); h.w = bf16_bits(acc[ej][3]);
            *(ushort4*)&Bht[((size_t)n * 64 + j0 + ej) * 128 + c0] = h;
        }
    }
}

// ---------------------------------------------------------------------------
// Kernel 2 (R13): fused scores + argmax, counted-vmcnt 3-deep pipeline.
//  - ldsB 3-deep (48 KB): kick cluster it+2; per-iter sync = vmcnt(4)+s_barrier
//    (waits only for loads issued a full iteration earlier -> near-free),
//    instead of __syncthreads' vmcnt(0) drain of the just-issued batch.
//  - score assembly round-robin: wave c&3 assembles cluster c, private top-2;
//    4-way merge at the end (ties force v1-v2 < TAU -> exact rescore decides).
//  - ldsA overlaid with scL (dead after frag load): total ~73 KB -> 2 blk/CU.
// MFMA fragments and 16-partial summation order identical to R12.
// ---------------------------------------------------------------------------
__global__ __launch_bounds__(256) void gemm_argmax(const unsigned short* __restrict__ xh,
                                                   const unsigned short* __restrict__ Bht,
                                                   const float* __restrict__ nrm,
                                                   const float* __restrict__ x,
                                                   const float* __restrict__ Qg,
                                                   float* __restrict__ out) {
    __shared__ __align__(16) unsigned short ldsB[3][64 * 128];   // 48 KB, 3-deep
    __shared__ __align__(16) unsigned char uniA[16704];          // ldsA (16KB) U scL (16.64KB)
    __shared__ float scPart[2][16][68];                          // 8.5 KB partials
    __shared__ int sflags[64];
    __shared__ int scnt;
    __shared__ float ssum;
    __shared__ float scorr[4];
    unsigned short* ldsA = (unsigned short*)uniA;
    float* scL = (float*)uniA;                                   // stride 65

    const int t = threadIdx.x, w = t >> 6, lane = t & 63;
    const int m0 = blockIdx.x * 64;
    const int lm = lane & 15, lg = lane >> 4;
    const int rl = lane >> 4, sp = lane & 15;
    if (t == 0) scnt = 0;
    if (t < 4) scorr[t] = 0.0f;

    // ---- prologue: stage A (xh) + B clusters 0,1 ----
    #pragma unroll
    for (int q = 0; q < 4; ++q) {
        const int row = w * 16 + q * 4 + rl;
        const int c = sp ^ (row & 15);
        gl_lds16(xh + (size_t)(m0 + row) * 128 + c * 8,
                 &ldsA[(w * 16 + q * 4) * 128]);
        gl_lds16(Bht + (size_t)row * 128 + c * 8,
                 &ldsB[0][(w * 16 + q * 4) * 128]);
        gl_lds16(Bht + ((size_t)64 + row) * 128 + c * 8,
                 &ldsB[1][(w * 16 + q * 4) * 128]);
    }
    __syncthreads();   // full drain: A, B0, B1 visible

    // ---- sample-frags register-resident (B-operand): 4 st x 4 ks ----
    s16x8 bf[4][4];
    #pragma unroll
    for (int st = 0; st < 4; ++st) {
        const int r = st * 16 + lm;
        #pragma unroll
        for (int ks = 0; ks < 4; ++ks) {
            const int p = (ks * 4 + lg) ^ (r & 15);
            bf[st][ks] = *(const s16x8*)&ldsA[r * 128 + p * 8];
        }
    }

    float v1 = -1e30f, v2 = -1e30f;   // per-wave top-2 over its assembled clusters
    int n1 = 0;

    #pragma unroll 1
    for (int it = 0; it < 64; ++it) {
        const int cur = it % 3;

        // this wave's j-quarter frags for cluster `it`
        s16x8 af[4];
        {
            const int r = w * 16 + lm;
            #pragma unroll
            for (int ks = 0; ks < 4; ++ks) {
                const int p = (ks * 4 + lg) ^ (r & 15);
                af[ks] = *(const s16x8*)&ldsB[cur][r * 128 + p * 8];
            }
        }

        // kick cluster it+2 into buffer (it+2)%3 (published at iter it+1's wait)
        if (it < 62) {
            const int nb = (it + 2) % 3;
            #pragma unroll
            for (int q = 0; q < 4; ++q) {
                const int row = w * 16 + q * 4 + rl;
                const int c = sp ^ (row & 15);
                gl_lds16(Bht + ((size_t)(it + 2) * 64 + row) * 128 + c * 8,
                         &ldsB[nb][(w * 16 + q * 4) * 128]);
            }
        }

        // round-robin assembly of cluster it-1 (reads scPart[(it-1)&1])
        if (it > 0 && w == ((it - 1) & 3)) {
            const int pb = (it - 1) & 1;
            float s = scPart[pb][0][lane];
            #pragma unroll
            for (int idx = 1; idx < 16; ++idx) s += scPart[pb][idx][lane];
            scL[lane * 65 + (it - 1)] = s;
            if (s > v1) { v2 = v1; v1 = s; n1 = it - 1; } else v2 = fmaxf(v2, s);
        }

        // MFMA: z[j][sample]; per lane acc regs = 4 j-rows of one sample
        #pragma unroll
        for (int st = 0; st < 4; ++st) {
            f32x4 acc = (f32x4){0.f, 0.f, 0.f, 0.f};
            #pragma unroll
            for (int ks = 0; ks < 4; ++ks)
                acc = __builtin_amdgcn_mfma_f32_16x16x32_bf16(af[ks], bf[st][ks], acc, 0, 0, 0);
            float q = acc[0] * acc[0];
            q = fmaf(acc[1], acc[1], q);
            q = fmaf(acc[2], acc[2], q);
            q = fmaf(acc[3], acc[3], q);
            scPart[it & 1][w * 4 + lg][st * 16 + lm] = q;
        }

        // counted-vmcnt publish: batch issued at it-1 is complete; batch from
        // this iter (<=4 outstanding) stays in flight across the barrier.
        if (it < 62) asm volatile("s_waitcnt vmcnt(4)" ::: "memory");
        else         asm volatile("s_waitcnt vmcnt(0)" ::: "memory");
        __builtin_amdgcn_s_barrier();
        __builtin_amdgcn_sched_barrier(0);
    }

    // final assembly: cluster 63 by wave 3 (partials in scPart[1])
    if (w == 3) {
        float s = scPart[1][0][lane];
        #pragma unroll
        for (int idx = 1; idx < 16; ++idx) s += scPart[1][idx][lane];
        scL[lane * 65 + 63] = s;
        if (s > v1) { v2 = v1; v1 = s; n1 = 63; } else v2 = fmaxf(v2, s);
    }

    // merge per-wave top-2 triples (overlay on scPart[0]; scPart[1] untouched)
    {
        float* mrg = &scPart[0][0][0];
        mrg[w * 192 + lane]       = v1;
        mrg[w * 192 + 64 + lane]  = v2;
        mrg[w * 192 + 128 + lane] = (float)n1;
    }
    __syncthreads();

    if (w == 0) {
        const float* mrg = &scPart[0][0][0];
        float b1 = -1e30f, b2 = -1e30f;
        int bn = 0;
        #pragma unroll
        for (int ww = 0; ww < 4; ++ww) {
            const float a1 = mrg[ww * 192 + lane];
            const float a2 = mrg[ww * 192 + 64 + lane];
            const int an = (int)mrg[ww * 192 + 128 + lane];
            if (a1 > b1) { b2 = fmaxf(b1, a2); b1 = a1; bn = an; }
            else b2 = fmaxf(b2, a1);
        }
        out[1 + m0 + lane] = (float)bn;
        if (b1 - b2 < TAU) { const int i = atomicAdd(&scnt, 1); sflags[i] = lane; }
        float err = nrm[m0 + lane] - b1;
        err += __shfl_xor(err, 1, 64);
        err += __shfl_xor(err, 2, 64);
        err += __shfl_xor(err, 4, 64);
        err += __shfl_xor(err, 8, 64);
        err += __shfl_xor(err, 16, 64);
        err += __shfl_xor(err, 32, 64);
        if (lane == 0) ssum = err;
    }
    __syncthreads();

    // cooperative exact rescore of flagged samples (S row from scL)
    const int nf = scnt;
    float corr = 0.0f;
    for (int f = w; f < nf; f += 4) {
        const int s = sflags[f];
        const int b2 = m0 + s;
        const float v = scL[s * 65 + lane];
        float vm = v;
        for (int off = 32; off; off >>= 1) vm = fmaxf(vm, __shfl_xor(vm, off, 64));
        unsigned long long mask = __ballot((vm - v) < TAU);
        float best = -1e30f;
        int bn = 0;
        while (mask) {
            const int nn = (int)__builtin_ctzll(mask);
            mask &= mask - 1;
            const float* Qn = Qg + (size_t)nn * 8192;
            const float* xb = x + (size_t)b2 * 128;
            float d0 = 0.0f, d1 = 0.0f, d2 = 0.0f, d3 = 0.0f;
            #pragma unroll
            for (int i = 0; i < 128; i += 4) {
                d0 = fmaf(Qn[(i + 0) * 64 + lane], xb[i + 0], d0);
                d1 = fmaf(Qn[(i + 1) * 64 + lane], xb[i + 1], d1);
                d2 = fmaf(Qn[(i + 2) * 64 + lane], xb[i + 2], d2);
                d3 = fmaf(Qn[(i + 3) * 64 + lane], xb[i + 3], d3);
            }
            const float dot = (d0 + d1) + (d2 + d3);
            float sv = dot * dot;
            for (int off = 32; off; off >>= 1) sv += __shfl_xor(sv, off, 64);
            if (sv > best) { best = sv; bn = nn; }
        }
        if (lane == 0) {
            out[1 + b2] = (float)bn;
            corr += vm - best;   // replace approx top score with exact best
        }
    }
    if (lane == 0 && corr != 0.0f) scorr[w] += corr;
    __syncthreads();
    if (t == 0)
        atomicAdd(out, ssum + scorr[0] + scorr[1] + scorr[2] + scorr[3]);
}

// ---------------------------------------------------------------------------
extern "C" void kernel_launch(void* const* d_in, const int* in_sizes, int n_in,
                              void* d_out, int out_size, void* d_ws, size_t ws_size,
                              hipStream_t stream) {
    const float* x = (const float*)d_in[0];   // [16384, 128]
    const float* D = (const float*)d_in[1];   // [64, 128, 64]
    float* out = (float*)d_out;               // [1 + 16384]

    char* ws = (char*)d_ws;
    unsigned short* xh  = (unsigned short*)(ws);                 // 4 MB
    unsigned short* Bht = (unsigned short*)(ws + (4u << 20));    // 1 MB
    float* Qg           = (float*)(ws + (5u << 20));             // 2 MB
    float* nrm          = (float*)(ws + (11u << 20));            // 64 KB

    prep_convert<<<192, 512, 0, stream>>>(x, D, xh, nrm, Qg, Bht, out);
    gemm_argmax<<<256, 256, 0, stream>>>(xh, Bht, nrm, x, Qg, out);
}